// Round 8
// baseline (306.627 us; speedup 1.0000x reference)
//
#include <hip/hip_runtime.h>
#include <hip/hip_fp8.h>
#include <cstdint>
#include <cstddef>

typedef unsigned short u16;
typedef _Float16 f16x8 __attribute__((ext_vector_type(8)));
typedef float f32x2 __attribute__((ext_vector_type(2)));
typedef float f32x4 __attribute__((ext_vector_type(4)));

#if defined(__has_builtin)
#if __has_builtin(__builtin_amdgcn_cvt_pk_f32_fp8) && __has_builtin(__builtin_amdgcn_cvt_pk_fp8_f32)
#define FP8_BUILTIN 1
#endif
#endif

__device__ __forceinline__ float h2f(u16 u) {
  return (float)__builtin_bit_cast(_Float16, u);
}
__device__ __forceinline__ u16 f2h(float f) {
  return __builtin_bit_cast(u16, (_Float16)f);
}
__device__ __forceinline__ unsigned pkh(float lo, float hi) {
  return (unsigned)f2h(lo) | ((unsigned)f2h(hi) << 16);
}
__device__ __forceinline__ unsigned char ftofp8(float f) {
#ifdef FP8_BUILTIN
  return (unsigned char)(__builtin_amdgcn_cvt_pk_fp8_f32(f, f, 0, false) & 0xFF);
#else
  return __hip_fp8_e4m3(f).__x;
#endif
}

// async 16B global -> LDS (gfx950)
__device__ __forceinline__ void async16(u16* lds, const u16* g) {
  __builtin_amdgcn_global_load_lds(
      (const __attribute__((address_space(1))) unsigned int*)g,
      (__attribute__((address_space(3))) unsigned int*)lds, 16, 0, 0);
}

// fp8 row chunk (8 bytes) -> f32x2 packed fma into a2[4] (v_pk_fma_f32 path)
__device__ __forceinline__ void fma8p2(f32x2* a2, float d, uint2 p) {
#ifdef FP8_BUILTIN
  f32x2 d2; d2[0] = d; d2[1] = d;
  f32x2 v0 = __builtin_amdgcn_cvt_pk_f32_fp8((int)p.x, false);
  f32x2 v1 = __builtin_amdgcn_cvt_pk_f32_fp8((int)p.x, true);
  f32x2 v2 = __builtin_amdgcn_cvt_pk_f32_fp8((int)p.y, false);
  f32x2 v3 = __builtin_amdgcn_cvt_pk_f32_fp8((int)p.y, true);
  a2[0] += d2 * v0; a2[1] += d2 * v1; a2[2] += d2 * v2; a2[3] += d2 * v3;
#else
  const unsigned char* b = (const unsigned char*)&p;
#pragma unroll
  for (int k = 0; k < 8; ++k) {
    __hip_fp8_e4m3 v; v.__x = b[k];
    a2[k >> 1][k & 1] += d * (float)v;
  }
#endif
}

// f16 row chunk (8 halves in uint4) -> fp32 fma
__device__ __forceinline__ void fma8h(float* a, float d, uint4 p) {
  const u16* q = (const u16*)&p;
#pragma unroll
  for (int k = 0; k < 8; ++k) a[k] += d * h2f(q[k]);
}

// fp32 row -> f16x8 fragment
__device__ __forceinline__ f16x8 cvt8(const float* p) {
  float4 a = *(const float4*)p;
  float4 b = *(const float4*)(p + 4);
  f16x8 r;
  r[0] = (_Float16)a.x; r[1] = (_Float16)a.y; r[2] = (_Float16)a.z; r[3] = (_Float16)a.w;
  r[4] = (_Float16)b.x; r[5] = (_Float16)b.y; r[6] = (_Float16)b.z; r[7] = (_Float16)b.w;
  return r;
}

// per-wave int64-vs-int32 edge dtype detection (first 1KB, L2-hot)
__device__ __forceinline__ int wave_is64(const void* ep) {
  const unsigned* p = (const unsigned*)ep;
  const int lane = threadIdx.x & 63;
  unsigned v = p[2 * lane + 1] | p[2 * (lane + 64) + 1];
  unsigned long long bal = __ballot(v != 0u);
  return (bal == 0ull) ? 1 : 0;
}

__device__ __forceinline__ int edge_at(const void* ep, int is64, long long idx) {
  if (is64) return (int)((const long long*)ep)[idx];
  return ((const int*)ep)[idx];
}

#define NCHUNK 256

// ---------------- diagnostics / fallback ----------------
__global__ void zero_f32(float* p, int n) {
  int i = blockIdx.x * 256 + threadIdx.x;
  if (i < n) p[i] = 0.f;
}

// ---------------- prep_all: 3x transpose_w + csr_hist ----------------
// cnt is chunk-major: cnt[chunk*256 + bucket]  (coalesced read/write)
__global__ __launch_bounds__(256) void prep_all(
    const float* __restrict__ W1, u16* __restrict__ wt1,
    const float* __restrict__ W2, u16* __restrict__ wt2,
    const float* __restrict__ W3, u16* __restrict__ wt3,
    const void* __restrict__ ep, int* __restrict__ cnt,
    int E, int N, int DIN, int DH, int DOUT,
    int nb_w1, int nb_w2, int nb_w3) {
  int b = blockIdx.x;
  if (b < nb_w1) {                        // wt1[n*DIN+k] = W1[k*DH+n]
    int idx = b * 256 + threadIdx.x;
    if (idx < DIN * DH) {
      int n = idx / DIN, k = idx % DIN;
      wt1[idx] = f2h(W1[k * DH + n]);
    }
    return;
  }
  b -= nb_w1;
  if (b < nb_w2) {                        // wt2[n*DH+k] = W2[k*DH+n]
    int idx = b * 256 + threadIdx.x;
    if (idx < DH * DH) {
      int n = idx / DH, k = idx % DH;
      wt2[idx] = f2h(W2[k * DH + n]);
    }
    return;
  }
  b -= nb_w2;
  if (b < nb_w3) {                        // wt3[n*DH+k] = W3[k*DOUT+n]
    int idx = b * 256 + threadIdx.x;
    if (idx < DH * DOUT) {
      int n = idx / DH, k = idx % DH;
      wt3[idx] = f2h(W3[k * DOUT + n]);
    }
    return;
  }
  b -= nb_w3;
  {                                       // per-chunk bucket histogram
    __shared__ int h[256];
    h[threadIdx.x] = 0;
    __syncthreads();
    int is64 = wave_is64(ep);
    const int per = (E + NCHUNK - 1) / NCHUNK;
    const int e0 = b * per, e1 = min(e0 + per, E);
    for (int e = e0 + (int)threadIdx.x; e < e1; e += 256) {
      int d = edge_at(ep, is64, (long long)E + e);
      d = min(max(d, 0), N - 1);
      atomicAdd(&h[d >> 8], 1);
    }
    __syncthreads();
    cnt[b * 256 + threadIdx.x] = h[threadIdx.x];
  }
}

// block-wide: compute exclusive bucket bases into bl[0..nbuck] (bl[nbuck]=E)
__device__ __forceinline__ void bases_in_lds(const int* __restrict__ cnt,
                                             int nbuck, int E, int* bl, int* ws4) {
  const int t = threadIdx.x, lane = t & 63, w = t >> 6;
  int tot = 0;
  if (t < nbuck) {
#pragma unroll 4
    for (int c = 0; c < NCHUNK; ++c) tot += cnt[c * 256 + t];
  }
  int inc = tot;
#pragma unroll
  for (int o = 1; o < 64; o <<= 1) {
    int u = __shfl_up(inc, o, 64);
    if (lane >= o) inc += u;
  }
  if (lane == 63) ws4[w] = inc;
  __syncthreads();
  if (t == 0) {
    int run = 0;
#pragma unroll
    for (int k = 0; k < 4; ++k) { int v = ws4[k]; ws4[k + 4] = run; run += v; }
  }
  __syncthreads();
  bl[t] = ws4[w + 4] + inc - tot;
  if (t == 0) bl[nbuck] = E;
  __syncthreads();
}

// csr_bucket: recompute bases per block, scatter chunk into bucket runs.
// Small LDS (~2KB) -> high occupancy; latency-bound scatter hides via TLP.
__global__ __launch_bounds__(256) void csr_bucket(const void* __restrict__ ep,
                                                  const int* __restrict__ cnt,
                                                  unsigned* __restrict__ tmp,
                                                  int E, int N, int nbuck) {
  __shared__ int bl[257];
  __shared__ int cur[256];
  __shared__ int ws4[8];
  const int chunk = blockIdx.x;
  const int t = threadIdx.x;
  bases_in_lds(cnt, nbuck, E, bl, ws4);
  if (t < nbuck) {
    int partial = 0;
    for (int c = 0; c < chunk; ++c) partial += cnt[c * 256 + t];
    cur[t] = bl[t] + partial;
  }
  __syncthreads();
  int is64 = wave_is64(ep);
  const int per = (E + NCHUNK - 1) / NCHUNK;
  const int e0 = chunk * per, e1 = min(e0 + per, E);
  for (int e = e0 + t; e < e1; e += 256) {
    int s = edge_at(ep, is64, e);
    int d = edge_at(ep, is64, (long long)E + e);
    s = min(max(s, 0), N - 1);
    d = min(max(d, 0), N - 1);
    int pos = atomicAdd(&cur[d >> 8], 1);
    tmp[pos] = ((unsigned)d << 16) | (unsigned)s;
  }
}

// csr_final: recompute bases, per-bucket node histogram -> rp/dis + col scatter
__global__ __launch_bounds__(256) void csr_final(const unsigned* __restrict__ tmp,
                                                 const int* __restrict__ cnt,
                                                 int* __restrict__ rp,
                                                 float* __restrict__ dis,
                                                 u16* __restrict__ col,
                                                 int N, int E, int nbuck) {
  __shared__ int bl[257];
  __shared__ int hcnt[256];
  __shared__ int curs[256];
  __shared__ int ws4[8];
  const int b = blockIdx.x;
  const int node0 = b * 256;
  const int t = threadIdx.x, lane = t & 63, w = t >> 6;
  bases_in_lds(cnt, nbuck, E, bl, ws4);
  const int k0 = bl[b], k1 = bl[b + 1];
  hcnt[t] = 0;
  __syncthreads();
  for (int k = k0 + t; k < k1; k += 256)
    atomicAdd(&hcnt[(int)(tmp[k] >> 16) - node0], 1);
  __syncthreads();
  const int v = hcnt[t];
  int inc = v;
#pragma unroll
  for (int o = 1; o < 64; o <<= 1) {
    int u = __shfl_up(inc, o, 64);
    if (lane >= o) inc += u;
  }
  __syncthreads();                        // ws4 reuse
  if (lane == 63) ws4[w] = inc;
  __syncthreads();
  if (t == 0) {
    int run = 0;
#pragma unroll
    for (int k = 0; k < 4; ++k) { int vv = ws4[k]; ws4[k + 4] = run; run += vv; }
  }
  __syncthreads();
  const int excl = k0 + ws4[w + 4] + inc - v;
  if (node0 + t < N) {
    rp[node0 + t] = excl;
    dis[node0 + t] = rsqrtf((float)(v + 1));   // +1 = self loop
  }
  if (b == 0 && t == 0) rp[N] = E;
  curs[t] = excl;
  __syncthreads();
  for (int k = k0 + t; k < k1; k += 256) {
    unsigned e = tmp[k];
    int dl = (int)(e >> 16) - node0;
    int pos = atomicAdd(&curs[dl], 1);
    col[pos] = (u16)(e & 0xFFFFu);
  }
}

// ---------------- B-resident GEMM, BN=64 col tiles looped in-block ----------
// Block: 128 A-rows (2 row-sets/wave), output width NBT*64; A read once.
// 32KB LDS -> 4 blocks/CU (vs 64KB/2 at BN=128): 2x occupancy ceiling.
// A32=1: A fp32 (layer 1, rows clamped). OUT8=1: C = fp8(SC*acc); else f16.
template <int OUT8, int A32, int NBT, int SC>
__global__ __launch_bounds__(256) void gemm64c(const void* __restrict__ A,
                                               const u16* __restrict__ Bt,
                                               void* __restrict__ Cv, int Nt,
                                               int Nrows) {
  constexpr int K = 256;
  constexpr int BN = 64;
  constexpr int NJ = 4;                    // BN/16
  constexpr int CH = BN * K / 8;           // 2048 16B-chunks
  __shared__ __align__(16) u16 Bs[BN * K]; // 32 KB

  const int tid = threadIdx.x, lane = tid & 63, w = tid >> 6;
  const int bm = blockIdx.x;

  auto stage = [&](int bt) {
#pragma unroll
    for (int i = 0; i < CH / 256; ++i) {   // 8 x async16 per thread
      int c = tid + i * 256;
      int ln = c & 63, t2 = c >> 6;        // t2: 0..31
      int ks = t2 & 7, j = t2 >> 3;        // ks 0..7, j 0..3
      int row = bt * BN + j * 16 + (ln & 15);
      int kk = ks * 32 + (ln >> 4) * 8;
      async16(&Bs[(size_t)c * 8], Bt + (size_t)row * K + kk);
    }
  };
  stage(0);

  const int r16 = lane & 15, quad = lane >> 4;
  const int m0 = w * 32;
  int row0 = bm * 128 + m0 + r16;
  int row1 = row0 + 16;
  f16x8 aa0[8], aa1[8];
  if (A32) {
    row0 = min(row0, Nrows - 1);
    row1 = min(row1, Nrows - 1);
    const float* A0 = (const float*)A + (size_t)row0 * K + quad * 8;
    const float* A1 = (const float*)A + (size_t)row1 * K + quad * 8;
#pragma unroll
    for (int ks = 0; ks < 8; ++ks) {
      aa0[ks] = cvt8(A0 + ks * 32);
      aa1[ks] = cvt8(A1 + ks * 32);
    }
  } else {
    const u16* A0 = (const u16*)A + (size_t)row0 * K + quad * 8;
    const u16* A1 = (const u16*)A + (size_t)row1 * K + quad * 8;
#pragma unroll
    for (int ks = 0; ks < 8; ++ks) {
      aa0[ks] = *(const f16x8*)(A0 + ks * 32);
      aa1[ks] = *(const f16x8*)(A1 + ks * 32);
    }
  }

  const f32x4 fzero = {0.f, 0.f, 0.f, 0.f};
#pragma unroll
  for (int bt = 0; bt < NBT; ++bt) {
    f32x4 acc[2][NJ];
#pragma unroll
    for (int i = 0; i < 2; ++i)
#pragma unroll
      for (int j = 0; j < NJ; ++j) acc[i][j] = fzero;
    __syncthreads();                       // Bs[bt] staged (vmcnt drained)
#pragma unroll
    for (int ks = 0; ks < 8; ++ks)
#pragma unroll
      for (int j = 0; j < NJ; ++j) {
        f16x8 bf = *(const f16x8*)(&Bs[(size_t)((j * 8 + ks) * 64 + lane) * 8]);
        acc[0][j] = __builtin_amdgcn_mfma_f32_16x16x32_f16(aa0[ks], bf, acc[0][j], 0, 0, 0);
        acc[1][j] = __builtin_amdgcn_mfma_f32_16x16x32_f16(aa1[ks], bf, acc[1][j], 0, 0, 0);
      }
    if (bt + 1 < NBT) {
      __syncthreads();                     // all waves done reading Bs[bt]
      stage(bt + 1);                       // overlap restage with C write
    }
#pragma unroll
    for (int i = 0; i < 2; ++i)
#pragma unroll
      for (int j = 0; j < NJ; ++j) {
        int gr = bm * 128 + m0 + i * 16 + quad * 4;  // C/D: col=lane&15, row=quad*4+r
        int gc = bt * BN + j * 16 + r16;
#pragma unroll
        for (int r = 0; r < 4; ++r) {
          if (OUT8) {
            ((unsigned char*)Cv)[(size_t)(gr + r) * Nt + gc] =
                ftofp8(acc[i][j][r] * (float)SC);
          } else {
            ((u16*)Cv)[(size_t)(gr + r) * Nt + gc] = f2h(acc[i][j][r]);
          }
        }
      }
  }
}

// ---------------- aggregation, d=256, fp8 rows (256B), fp32 acc -------------
// Per-node blocks (4 waves x 1 node). 32 lanes/row x 8B (uint2), 2 edge slots.
// 2-stage software pipeline + JUNK-GATHER CLAMP: tail lanes load col[e1-1]'s
// row (same line as a valid lane -> coalesced L2 hit, no random HBM line);
// contribution still masked by d=0 predicate. Kills ~22% junk HBM traffic.
// SCALED=1: h rows are fp8(4*dis[src]*msg) — no dis gather; sum scaled by 1/4.
// Output: xpad[i] = dis[i] * relu(dis[i]*sum*inv + bias)  [pre-scaled for next
// GEMM, which makes the next layer's agg SCALED].
template <int SCALED>
__global__ __launch_bounds__(256) void agg_d256(const unsigned char* __restrict__ h,
                                                const int* __restrict__ rp,
                                                const u16* __restrict__ col,
                                                const float* __restrict__ dis,
                                                const float* __restrict__ bias,
                                                u16* __restrict__ out, int N) {
  const int wid = threadIdx.x >> 6, lane = threadIdx.x & 63;
  const int i = blockIdx.x * 4 + wid;
  if (i >= N) return;
  const int sub = lane >> 5;            // 2 edge slots
  const int l32 = lane & 31;
  const int c8 = l32 * 8;               // byte offset (fp8) == elem offset (f16)
  const float di = dis[i];
  f32x2 a2[4];
#pragma unroll
  for (int k = 0; k < 4; ++k) { a2[k][0] = 0.f; a2[k][1] = 0.f; }
  uint2 sv = make_uint2(0u, 0u);
  if (sub == 0)                         // self-term load issued early
    sv = *(const uint2*)(h + (size_t)i * 256 + c8);
  const int e1 = rp[i + 1];
  for (int base = rp[i]; base < e1; base += 64) {
    const int me = base + lane;
    // clamp: junk lanes alias the last valid edge's src row (cheap, masked)
    int s_l = (int)col[min(me, e1 - 1)];
    float d_l = 0.f;
    if (!SCALED && me < e1) d_l = dis[s_l];
    const int cnt = min(64, e1 - base);
    const int cntR = (cnt + 7) & ~7;
    // prologue: group 0
    int sA = __shfl(s_l, sub, 64),     sB = __shfl(s_l, 2 + sub, 64);
    int sC = __shfl(s_l, 4 + sub, 64), sD = __shfl(s_l, 6 + sub, 64);
    float dA, dB, dC, dD;
    if (SCALED) {
      dA = (sub < cnt) ? 1.f : 0.f;     dB = (2 + sub < cnt) ? 1.f : 0.f;
      dC = (4 + sub < cnt) ? 1.f : 0.f; dD = (6 + sub < cnt) ? 1.f : 0.f;
    } else {
      dA = __shfl(d_l, sub, 64);     dB = __shfl(d_l, 2 + sub, 64);
      dC = __shfl(d_l, 4 + sub, 64); dD = __shfl(d_l, 6 + sub, 64);
    }
    uint2 pA = *(const uint2*)(h + (size_t)sA * 256 + c8);
    uint2 pB = *(const uint2*)(h + (size_t)sB * 256 + c8);
    uint2 pC = *(const uint2*)(h + (size_t)sC * 256 + c8);
    uint2 pD = *(const uint2*)(h + (size_t)sD * 256 + c8);
    for (int t = 0; t < cntR; t += 8) {
      uint2 qA = pA, qB = pB, qC = pC, qD = pD;
      float eA = dA, eB = dB, eC = dC, eD = dD;
      const int nt = t + 8;
      if (nt < cntR) {                  // prefetch next group (uniform branch)
        sA = __shfl(s_l, nt + sub, 64);     sB = __shfl(s_l, nt + 2 + sub, 64);
        sC = __shfl(s_l, nt + 4 + sub, 64); sD = __shfl(s_l, nt + 6 + sub, 64);
        if (SCALED) {
          dA = (nt + sub < cnt) ? 1.f : 0.f;
          dB = (nt + 2 + sub < cnt) ? 1.f : 0.f;
          dC = (nt + 4 + sub < cnt) ? 1.f : 0.f;
          dD = (nt + 6 + sub < cnt) ? 1.f : 0.f;
        } else {
          dA = __shfl(d_l, nt + sub, 64);     dB = __shfl(d_l, nt + 2 + sub, 64);
          dC = __shfl(d_l, nt + 4 + sub, 64); dD = __shfl(d_l, nt + 6 + sub, 64);
        }
        pA = *(const uint2*)(h + (size_t)sA * 256 + c8);
        pB = *(const uint2*)(h + (size_t)sB * 256 + c8);
        pC = *(const uint2*)(h + (size_t)sC * 256 + c8);
        pD = *(const uint2*)(h + (size_t)sD * 256 + c8);
      }
      fma8p2(a2, eA, qA); fma8p2(a2, eB, qB);
      fma8p2(a2, eC, qC); fma8p2(a2, eD, qD);
    }
  }
  if (sub == 0)                         // self term (reordered: added last)
    fma8p2(a2, SCALED ? 1.f : di, sv);
#pragma unroll
  for (int k = 0; k < 4; ++k) {
    a2[k][0] += __shfl_xor(a2[k][0], 32, 64);
    a2[k][1] += __shfl_xor(a2[k][1], 32, 64);
  }
  if (sub == 0) {
    const float inv = SCALED ? 0.25f : 1.f;   // undo SC=4 fp8 pre-scale
    float4 b0 = *(const float4*)(bias + c8);
    float4 b1 = *(const float4*)(bias + c8 + 4);
    float bb[8] = {b0.x, b0.y, b0.z, b0.w, b1.x, b1.y, b1.z, b1.w};
    float r[8];
#pragma unroll
    for (int k = 0; k < 8; ++k)
      r[k] = fmaxf(di * a2[k >> 1][k & 1] * inv + bb[k], 0.f) * di;
    uint4 ov;
    ov.x = pkh(r[0], r[1]); ov.y = pkh(r[2], r[3]);
    ov.z = pkh(r[4], r[5]); ov.w = pkh(r[6], r[7]);
    *(uint4*)(out + (size_t)i * 256 + c8) = ov;   // prescaled f16 for next GEMM
  }
}

// final layer: h f16 [N,64] already-scaled messages (dis[src]*h3), out fp32.
// Same 2-stage pipeline + junk-gather clamp (round-to-16 waste ~47% -> L2 hits).
__global__ __launch_bounds__(256) void agg_d64(const u16* __restrict__ h,
                                               const int* __restrict__ rp,
                                               const u16* __restrict__ col,
                                               const float* __restrict__ dis,
                                               const float* __restrict__ bias,
                                               float* __restrict__ out, int N) {
  const int wid = threadIdx.x >> 6, lane = threadIdx.x & 63;
  const int i = blockIdx.x * 4 + wid;
  if (i >= N) return;
  const int grp = lane >> 3;      // edge slot 0..7
  const int l8 = lane & 7;
  const int c8 = l8 * 8;          // feature offset, 8 features/lane (16B f16)
  const float di = dis[i];
  float a[8] = {0.f, 0.f, 0.f, 0.f, 0.f, 0.f, 0.f, 0.f};
  uint4 sv = make_uint4(0u, 0u, 0u, 0u);
  if (grp == 0)                   // self-term load issued early
    sv = *(const uint4*)(h + (size_t)i * 64 + c8);
  const int e1 = rp[i + 1];
  for (int base = rp[i]; base < e1; base += 64) {
    const int me = base + lane;
    // clamp: junk lanes alias the last valid edge's src row (cheap, masked)
    int s_l = (int)col[min(me, e1 - 1)];
    const int cnt = min(64, e1 - base);
    const int cntR = (cnt + 15) & ~15;
    // prologue: group 0
    int sA = __shfl(s_l, grp, 64), sB = __shfl(s_l, 8 + grp, 64);
    float dA = (grp < cnt) ? 1.f : 0.f;
    float dB = (8 + grp < cnt) ? 1.f : 0.f;
    uint4 pA = *(const uint4*)(h + (size_t)sA * 64 + c8);
    uint4 pB = *(const uint4*)(h + (size_t)sB * 64 + c8);
    for (int t = 0; t < cntR; t += 16) {
      uint4 qA = pA, qB = pB;
      float eA = dA, eB = dB;
      const int nt = t + 16;
      if (nt < cntR) {            // prefetch next group (uniform branch)
        sA = __shfl(s_l, nt + grp, 64);
        sB = __shfl(s_l, nt + 8 + grp, 64);
        dA = (nt + grp < cnt) ? 1.f : 0.f;
        dB = (nt + 8 + grp < cnt) ? 1.f : 0.f;
        pA = *(const uint4*)(h + (size_t)sA * 64 + c8);
        pB = *(const uint4*)(h + (size_t)sB * 64 + c8);
      }
      fma8h(a, eA, qA); fma8h(a, eB, qB);
    }
  }
  if (grp == 0) fma8h(a, 1.f, sv);  // self term (input pre-scaled)
#pragma unroll
  for (int k = 0; k < 8; ++k) a[k] += __shfl_xor(a[k], 8, 64);
#pragma unroll
  for (int k = 0; k < 8; ++k) a[k] += __shfl_xor(a[k], 16, 64);
#pragma unroll
  for (int k = 0; k < 8; ++k) a[k] += __shfl_xor(a[k], 32, 64);
  if (lane < 8) {
    float4 b0 = *(const float4*)(bias + c8);
    float4 b1 = *(const float4*)(bias + c8 + 4);
    float4 o0, o1;
    o0.x = di * a[0] + b0.x; o0.y = di * a[1] + b0.y;
    o0.z = di * a[2] + b0.z; o0.w = di * a[3] + b0.w;
    o1.x = di * a[4] + b1.x; o1.y = di * a[5] + b1.y;
    o1.z = di * a[6] + b1.z; o1.w = di * a[7] + b1.w;
    *(float4*)(out + (size_t)i * 64 + c8) = o0;
    *(float4*)(out + (size_t)i * 64 + c8 + 4) = o1;
  }
}

// ---------------- launch ----------------
extern "C" void kernel_launch(void* const* d_in, const int* in_sizes, int n_in,
                              void* d_out, int out_size, void* d_ws, size_t ws_size,
                              hipStream_t stream) {
  if (n_in < 8) return;
  const float* x = (const float*)d_in[0];
  const void* eptr = d_in[1];
  const float* W1 = (const float*)d_in[2];
  const float* b1 = (const float*)d_in[3];
  const float* W2 = (const float*)d_in[4];
  const float* b2 = (const float*)d_in[5];
  const float* W3 = (const float*)d_in[6];
  const float* b3 = (const float*)d_in[7];
  float* out = (float*)d_out;

  const int DIN = 256, DH = 256;
  const int N = in_sizes[0] / DIN;       // 50000
  const int E = in_sizes[1] / 2;         // 800000
  const int DOUT = in_sizes[6] / DH;     // 64
  const int MT = (N + 127) / 128;        // 391
  const int Mpad = MT * 128;
  const int nbuck = (N + 255) >> 8;      // 196

  auto rnd = [](size_t b) { return (b + 255) & ~(size_t)255; };
  size_t required = 0;
  required += rnd((size_t)Mpad * DH * 2);            // xpad (f16 layer-2/3 input)
  required += rnd((size_t)Mpad * DH);                // hbuf (fp8 256B / f16 128B)
  required += rnd((size_t)E * 2);                    // col (u16)
  required += rnd((size_t)E * 4);                    // tmp (packed pairs)
  required += rnd((size_t)(N + 1) * 4);              // rp
  required += rnd((size_t)N * 4);                    // dis
  required += rnd((size_t)DIN * DH * 2);             // wt1
  required += rnd((size_t)DH * DH * 2);              // wt2
  required += rnd((size_t)DH * DOUT * 2);            // wt3
  required += rnd((size_t)256 * NCHUNK * 4);         // cnt
  if (ws_size < required || N > 65536 || nbuck > 256 || nbuck < 1 ||
      E < 128 || DOUT != 64) {
    zero_f32<<<(out_size + 255) / 256, 256, 0, stream>>>(out, out_size);
    return;
  }

  char* ws = (char*)d_ws;
  size_t off0 = 0;
  auto alloc = [&](size_t bytes) {
    char* p = ws + off0;
    off0 = (off0 + bytes + 255) & ~(size_t)255;
    return p;
  };
  u16* xpad = (u16*)alloc((size_t)Mpad * DH * 2);
  unsigned char* hbuf = (unsigned char*)alloc((size_t)Mpad * DH);
  u16* colb = (u16*)alloc((size_t)E * 2);
  unsigned* tmpb = (unsigned*)alloc((size_t)E * 4);
  int* rp = (int*)alloc((size_t)(N + 1) * 4);
  float* dis = (float*)alloc((size_t)N * 4);
  u16* wt1 = (u16*)alloc((size_t)DIN * DH * 2);
  u16* wt2 = (u16*)alloc((size_t)DH * DH * 2);
  u16* wt3 = (u16*)alloc((size_t)DH * DOUT * 2);
  int* cnt = (int*)alloc((size_t)256 * NCHUNK * 4);

  const int nb_w1 = (DIN * DH + 255) / 256;
  const int nb_w2 = (DH * DH + 255) / 256;
  const int nb_w3 = (DH * DOUT + 255) / 256;
  prep_all<<<nb_w1 + nb_w2 + nb_w3 + NCHUNK, 256, 0, stream>>>(
      W1, wt1, W2, wt2, W3, wt3, eptr, cnt,
      E, N, DIN, DH, DOUT, nb_w1, nb_w2, nb_w3);

  csr_bucket<<<NCHUNK, 256, 0, stream>>>(eptr, cnt, tmpb, E, N, nbuck);
  csr_final<<<nbuck, 256, 0, stream>>>(tmpb, cnt, rp, dis, colb, N, E, nbuck);

  const int gb = (N + 3) / 4;             // per-node agg blocks (measured best)

  // layer 1: gemm fp32-A -> fp8 h; agg with dis gather -> prescaled f16 xpad
  gemm64c<1, 1, 4, 1><<<MT, 256, 0, stream>>>(x, wt1, hbuf, DH, N);
  agg_d256<0><<<gb, 256, 0, stream>>>(hbuf, rp, colb, dis, b1, xpad, N);
  // layer 2: gemm f16-A (prescaled) -> fp8(4*dis*h); agg without dis gather
  gemm64c<1, 0, 4, 4><<<MT, 256, 0, stream>>>(xpad, wt2, hbuf, DH, N);
  agg_d256<1><<<gb, 256, 0, stream>>>(hbuf, rp, colb, dis, b2, xpad, N);
  // layer 3: gemm -> f16 scaled msgs (128B rows); agg_d64 -> fp32 out
  gemm64c<0, 0, 1, 1><<<MT, 256, 0, stream>>>(xpad, wt3, hbuf, DOUT, N);
  agg_d64<<<gb, 256, 0, stream>>>((const u16*)hbuf, rp, colb, dis, b3, out, N);
}

// Round 9
// 279.544 us; speedup vs baseline: 1.0969x; 1.0969x over previous
//
#include <hip/hip_runtime.h>
#include <hip/hip_fp8.h>
#include <cstdint>
#include <cstddef>

typedef unsigned short u16;
typedef _Float16 f16x8 __attribute__((ext_vector_type(8)));
typedef float f32x2 __attribute__((ext_vector_type(2)));
typedef float f32x4 __attribute__((ext_vector_type(4)));

#if defined(__has_builtin)
#if __has_builtin(__builtin_amdgcn_cvt_pk_f32_fp8) && __has_builtin(__builtin_amdgcn_cvt_pk_fp8_f32)
#define FP8_BUILTIN 1
#endif
#endif

__device__ __forceinline__ float h2f(u16 u) {
  return (float)__builtin_bit_cast(_Float16, u);
}
__device__ __forceinline__ u16 f2h(float f) {
  return __builtin_bit_cast(u16, (_Float16)f);
}
__device__ __forceinline__ unsigned pkh(float lo, float hi) {
  return (unsigned)f2h(lo) | ((unsigned)f2h(hi) << 16);
}
__device__ __forceinline__ unsigned char ftofp8(float f) {
#ifdef FP8_BUILTIN
  return (unsigned char)(__builtin_amdgcn_cvt_pk_fp8_f32(f, f, 0, false) & 0xFF);
#else
  return __hip_fp8_e4m3(f).__x;
#endif
}

// async 16B global -> LDS (gfx950)
__device__ __forceinline__ void async16(u16* lds, const u16* g) {
  __builtin_amdgcn_global_load_lds(
      (const __attribute__((address_space(1))) unsigned int*)g,
      (__attribute__((address_space(3))) unsigned int*)lds, 16, 0, 0);
}

// fp8 row chunk (8 bytes) -> f32x2 packed fma into a2[4] (v_pk_fma_f32 path)
__device__ __forceinline__ void fma8p2(f32x2* a2, float d, uint2 p) {
#ifdef FP8_BUILTIN
  f32x2 d2; d2[0] = d; d2[1] = d;
  f32x2 v0 = __builtin_amdgcn_cvt_pk_f32_fp8((int)p.x, false);
  f32x2 v1 = __builtin_amdgcn_cvt_pk_f32_fp8((int)p.x, true);
  f32x2 v2 = __builtin_amdgcn_cvt_pk_f32_fp8((int)p.y, false);
  f32x2 v3 = __builtin_amdgcn_cvt_pk_f32_fp8((int)p.y, true);
  a2[0] += d2 * v0; a2[1] += d2 * v1; a2[2] += d2 * v2; a2[3] += d2 * v3;
#else
  const unsigned char* b = (const unsigned char*)&p;
#pragma unroll
  for (int k = 0; k < 8; ++k) {
    __hip_fp8_e4m3 v; v.__x = b[k];
    a2[k >> 1][k & 1] += d * (float)v;
  }
#endif
}

// fp8 row chunk (16 bytes) -> f32x2 packed fma into a2[8]
__device__ __forceinline__ void fma16p2(f32x2* a2, float d, uint4 p) {
  fma8p2(a2, d, make_uint2(p.x, p.y));
  fma8p2(a2 + 4, d, make_uint2(p.z, p.w));
}

// f16 row chunk (8 halves in uint4) -> fp32 fma
__device__ __forceinline__ void fma8h(float* a, float d, uint4 p) {
  const u16* q = (const u16*)&p;
#pragma unroll
  for (int k = 0; k < 8; ++k) a[k] += d * h2f(q[k]);
}

// fp32 row -> f16x8 fragment
__device__ __forceinline__ f16x8 cvt8(const float* p) {
  float4 a = *(const float4*)p;
  float4 b = *(const float4*)(p + 4);
  f16x8 r;
  r[0] = (_Float16)a.x; r[1] = (_Float16)a.y; r[2] = (_Float16)a.z; r[3] = (_Float16)a.w;
  r[4] = (_Float16)b.x; r[5] = (_Float16)b.y; r[6] = (_Float16)b.z; r[7] = (_Float16)b.w;
  return r;
}

// per-wave int64-vs-int32 edge dtype detection (first 1KB, L2-hot)
__device__ __forceinline__ int wave_is64(const void* ep) {
  const unsigned* p = (const unsigned*)ep;
  const int lane = threadIdx.x & 63;
  unsigned v = p[2 * lane + 1] | p[2 * (lane + 64) + 1];
  unsigned long long bal = __ballot(v != 0u);
  return (bal == 0ull) ? 1 : 0;
}

__device__ __forceinline__ int edge_at(const void* ep, int is64, long long idx) {
  if (is64) return (int)((const long long*)ep)[idx];
  return ((const int*)ep)[idx];
}

#define NCHUNK 256

// ---------------- diagnostics / fallback ----------------
__global__ void zero_f32(float* p, int n) {
  int i = blockIdx.x * 256 + threadIdx.x;
  if (i < n) p[i] = 0.f;
}

// ---------------- prep_all: 3x transpose_w + csr_hist ----------------
// cnt is chunk-major: cnt[chunk*256 + bucket]  (coalesced read/write)
__global__ __launch_bounds__(256) void prep_all(
    const float* __restrict__ W1, u16* __restrict__ wt1,
    const float* __restrict__ W2, u16* __restrict__ wt2,
    const float* __restrict__ W3, u16* __restrict__ wt3,
    const void* __restrict__ ep, int* __restrict__ cnt,
    int E, int N, int DIN, int DH, int DOUT,
    int nb_w1, int nb_w2, int nb_w3) {
  int b = blockIdx.x;
  if (b < nb_w1) {                        // wt1[n*DIN+k] = W1[k*DH+n]
    int idx = b * 256 + threadIdx.x;
    if (idx < DIN * DH) {
      int n = idx / DIN, k = idx % DIN;
      wt1[idx] = f2h(W1[k * DH + n]);
    }
    return;
  }
  b -= nb_w1;
  if (b < nb_w2) {                        // wt2[n*DH+k] = W2[k*DH+n]
    int idx = b * 256 + threadIdx.x;
    if (idx < DH * DH) {
      int n = idx / DH, k = idx % DH;
      wt2[idx] = f2h(W2[k * DH + n]);
    }
    return;
  }
  b -= nb_w2;
  if (b < nb_w3) {                        // wt3[n*DH+k] = W3[k*DOUT+n]
    int idx = b * 256 + threadIdx.x;
    if (idx < DH * DOUT) {
      int n = idx / DH, k = idx % DH;
      wt3[idx] = f2h(W3[k * DOUT + n]);
    }
    return;
  }
  b -= nb_w3;
  {                                       // per-chunk bucket histogram
    __shared__ int h[256];
    h[threadIdx.x] = 0;
    __syncthreads();
    int is64 = wave_is64(ep);
    const int per = (E + NCHUNK - 1) / NCHUNK;
    const int e0 = b * per, e1 = min(e0 + per, E);
    for (int e = e0 + (int)threadIdx.x; e < e1; e += 256) {
      int d = edge_at(ep, is64, (long long)E + e);
      d = min(max(d, 0), N - 1);
      atomicAdd(&h[d >> 8], 1);
    }
    __syncthreads();
    cnt[b * 256 + threadIdx.x] = h[threadIdx.x];
  }
}

// block-wide: compute exclusive bucket bases into bl[0..nbuck] (bl[nbuck]=E)
__device__ __forceinline__ void bases_in_lds(const int* __restrict__ cnt,
                                             int nbuck, int E, int* bl, int* ws4) {
  const int t = threadIdx.x, lane = t & 63, w = t >> 6;
  int tot = 0;
  if (t < nbuck) {
#pragma unroll 4
    for (int c = 0; c < NCHUNK; ++c) tot += cnt[c * 256 + t];
  }
  int inc = tot;
#pragma unroll
  for (int o = 1; o < 64; o <<= 1) {
    int u = __shfl_up(inc, o, 64);
    if (lane >= o) inc += u;
  }
  if (lane == 63) ws4[w] = inc;
  __syncthreads();
  if (t == 0) {
    int run = 0;
#pragma unroll
    for (int k = 0; k < 4; ++k) { int v = ws4[k]; ws4[k + 4] = run; run += v; }
  }
  __syncthreads();
  bl[t] = ws4[w + 4] + inc - tot;
  if (t == 0) bl[nbuck] = E;
  __syncthreads();
}

// ---------------- B-resident GEMM body, BN=64 col tiles looped in-block -----
// Block: 128 A-rows (2 row-sets/wave), output width NBT*64; A read once.
// 32KB LDS -> 5 blocks/CU. A32=1: A fp32 (rows clamped). OUT8: fp8(SC*acc).
template <int OUT8, int A32, int NBT, int SC>
__device__ __forceinline__ void gemm64_dev(const void* __restrict__ A,
                                           const u16* __restrict__ Bt,
                                           void* __restrict__ Cv, int Nt,
                                           int Nrows, int bm, u16* Bs) {
  constexpr int K = 256;
  constexpr int BN = 64;
  constexpr int NJ = 4;                    // BN/16
  constexpr int CH = BN * K / 8;           // 2048 16B-chunks

  const int tid = threadIdx.x, lane = tid & 63, w = tid >> 6;

  auto stage = [&](int bt) {
#pragma unroll
    for (int i = 0; i < CH / 256; ++i) {   // 8 x async16 per thread
      int c = tid + i * 256;
      int ln = c & 63, t2 = c >> 6;        // t2: 0..31
      int ks = t2 & 7, j = t2 >> 3;        // ks 0..7, j 0..3
      int row = bt * BN + j * 16 + (ln & 15);
      int kk = ks * 32 + (ln >> 4) * 8;
      async16(&Bs[(size_t)c * 8], Bt + (size_t)row * K + kk);
    }
  };
  stage(0);

  const int r16 = lane & 15, quad = lane >> 4;
  const int m0 = w * 32;
  int row0 = bm * 128 + m0 + r16;
  int row1 = row0 + 16;
  f16x8 aa0[8], aa1[8];
  if (A32) {
    row0 = min(row0, Nrows - 1);
    row1 = min(row1, Nrows - 1);
    const float* A0 = (const float*)A + (size_t)row0 * K + quad * 8;
    const float* A1 = (const float*)A + (size_t)row1 * K + quad * 8;
#pragma unroll
    for (int ks = 0; ks < 8; ++ks) {
      aa0[ks] = cvt8(A0 + ks * 32);
      aa1[ks] = cvt8(A1 + ks * 32);
    }
  } else {
    const u16* A0 = (const u16*)A + (size_t)row0 * K + quad * 8;
    const u16* A1 = (const u16*)A + (size_t)row1 * K + quad * 8;
#pragma unroll
    for (int ks = 0; ks < 8; ++ks) {
      aa0[ks] = *(const f16x8*)(A0 + ks * 32);
      aa1[ks] = *(const f16x8*)(A1 + ks * 32);
    }
  }

  const f32x4 fzero = {0.f, 0.f, 0.f, 0.f};
#pragma unroll
  for (int bt = 0; bt < NBT; ++bt) {
    f32x4 acc[2][NJ];
#pragma unroll
    for (int i = 0; i < 2; ++i)
#pragma unroll
      for (int j = 0; j < NJ; ++j) acc[i][j] = fzero;
    __syncthreads();                       // Bs[bt] staged (vmcnt drained)
#pragma unroll
    for (int ks = 0; ks < 8; ++ks)
#pragma unroll
      for (int j = 0; j < NJ; ++j) {
        f16x8 bf = *(const f16x8*)(&Bs[(size_t)((j * 8 + ks) * 64 + lane) * 8]);
        acc[0][j] = __builtin_amdgcn_mfma_f32_16x16x32_f16(aa0[ks], bf, acc[0][j], 0, 0, 0);
        acc[1][j] = __builtin_amdgcn_mfma_f32_16x16x32_f16(aa1[ks], bf, acc[1][j], 0, 0, 0);
      }
    if (bt + 1 < NBT) {
      __syncthreads();                     // all waves done reading Bs[bt]
      stage(bt + 1);                       // overlap restage with C write
    }
#pragma unroll
    for (int i = 0; i < 2; ++i)
#pragma unroll
      for (int j = 0; j < NJ; ++j) {
        int gr = bm * 128 + m0 + i * 16 + quad * 4;  // C/D: col=lane&15, row=quad*4+r
        int gc = bt * BN + j * 16 + r16;
#pragma unroll
        for (int r = 0; r < 4; ++r) {
          if (OUT8) {
            ((unsigned char*)Cv)[(size_t)(gr + r) * Nt + gc] =
                ftofp8(acc[i][j][r] * (float)SC);
          } else {
            ((u16*)Cv)[(size_t)(gr + r) * Nt + gc] = f2h(acc[i][j][r]);
          }
        }
      }
  }
}

template <int OUT8, int A32, int NBT, int SC>
__global__ __launch_bounds__(256) void gemm64c(const void* __restrict__ A,
                                               const u16* __restrict__ Bt,
                                               void* __restrict__ Cv, int Nt,
                                               int Nrows) {
  __shared__ __align__(16) u16 Bs[64 * 256];  // 32 KB
  gemm64_dev<OUT8, A32, NBT, SC>(A, Bt, Cv, Nt, Nrows, (int)blockIdx.x, Bs);
}

// ---- fat kernel: csr_bucket (blocks 0..NCHUNK-1) || gemm layer-1 (rest) ----
// 32KB LDS -> 5 blocks/CU -> 1280 resident slots >= 647 total blocks: both
// phases fully co-resident, bucket scatter hides under gemm1 MFMA.
// (R1's 64KB version had only 512 slots -> serialization; this fixes it.)
__global__ __launch_bounds__(256) void bucket_gemm1(
    const void* __restrict__ ep, const int* __restrict__ cnt,
    unsigned* __restrict__ tmp, const float* __restrict__ x,
    const u16* __restrict__ wt1, unsigned char* __restrict__ hbuf,
    int E, int N, int nbuck) {
  __shared__ __align__(16) u16 Bs[64 * 256];  // 32 KB, shared by both paths
  if ((int)blockIdx.x >= NCHUNK) {
    gemm64_dev<1, 1, 4, 1>(x, wt1, hbuf, 256, N, (int)blockIdx.x - NCHUNK, Bs);
    return;
  }
  int* bl = (int*)Bs;                 // [257]
  int* cur = bl + 272;                // [256]
  int* ws4 = cur + 256;               // [8]
  const int chunk = blockIdx.x;
  const int t = threadIdx.x;
  bases_in_lds(cnt, nbuck, E, bl, ws4);
  if (t < nbuck) {
    int partial = 0;
    for (int c = 0; c < chunk; ++c) partial += cnt[c * 256 + t];
    cur[t] = bl[t] + partial;
  }
  __syncthreads();
  int is64 = wave_is64(ep);
  const int per = (E + NCHUNK - 1) / NCHUNK;
  const int e0 = chunk * per, e1 = min(e0 + per, E);
  for (int e = e0 + t; e < e1; e += 256) {
    int s = edge_at(ep, is64, e);
    int d = edge_at(ep, is64, (long long)E + e);
    s = min(max(s, 0), N - 1);
    d = min(max(d, 0), N - 1);
    int pos = atomicAdd(&cur[d >> 8], 1);
    tmp[pos] = ((unsigned)d << 16) | (unsigned)s;
  }
}

// csr_final: recompute bases, per-bucket node histogram -> rp/dis + col scatter
__global__ __launch_bounds__(256) void csr_final(const unsigned* __restrict__ tmp,
                                                 const int* __restrict__ cnt,
                                                 int* __restrict__ rp,
                                                 float* __restrict__ dis,
                                                 u16* __restrict__ col,
                                                 int N, int E, int nbuck) {
  __shared__ int bl[257];
  __shared__ int hcnt[256];
  __shared__ int curs[256];
  __shared__ int ws4[8];
  const int b = blockIdx.x;
  const int node0 = b * 256;
  const int t = threadIdx.x, lane = t & 63, w = t >> 6;
  bases_in_lds(cnt, nbuck, E, bl, ws4);
  const int k0 = bl[b], k1 = bl[b + 1];
  hcnt[t] = 0;
  __syncthreads();
  for (int k = k0 + t; k < k1; k += 256)
    atomicAdd(&hcnt[(int)(tmp[k] >> 16) - node0], 1);
  __syncthreads();
  const int v = hcnt[t];
  int inc = v;
#pragma unroll
  for (int o = 1; o < 64; o <<= 1) {
    int u = __shfl_up(inc, o, 64);
    if (lane >= o) inc += u;
  }
  __syncthreads();                        // ws4 reuse
  if (lane == 63) ws4[w] = inc;
  __syncthreads();
  if (t == 0) {
    int run = 0;
#pragma unroll
    for (int k = 0; k < 4; ++k) { int vv = ws4[k]; ws4[k + 4] = run; run += vv; }
  }
  __syncthreads();
  const int excl = k0 + ws4[w + 4] + inc - v;
  if (node0 + t < N) {
    rp[node0 + t] = excl;
    dis[node0 + t] = rsqrtf((float)(v + 1));   // +1 = self loop
  }
  if (b == 0 && t == 0) rp[N] = E;
  curs[t] = excl;
  __syncthreads();
  for (int k = k0 + t; k < k1; k += 256) {
    unsigned e = tmp[k];
    int dl = (int)(e >> 16) - node0;
    int pos = atomicAdd(&curs[dl], 1);
    col[pos] = (u16)(e & 0xFFFFu);
  }
}

// ---------------- aggregation, d=256, fp8 rows (256B), fp32 acc -------------
// 16 lanes/row x 16B (uint4), 4 edge slots, t+=8: per 8 edges only 2 shuffles
// + 2 gathers per lane (vs 4+4 at 32-lane/uint2) — kernel is issue-bound, so
// instruction count is the lever. Round-to-8 padding unchanged; junk lanes
// gather row col[0]-default (L2-hot, d=0-masked).
// SCALED=1: h rows are fp8(4*dis[src]*msg) — no dis gather; sum scaled by 1/4.
// Output: xpad[i] = dis[i] * relu(dis[i]*sum*inv + bias)  [pre-scaled for next
// GEMM, which makes the next layer's agg SCALED].
template <int SCALED>
__global__ __launch_bounds__(256) void agg_d256(const unsigned char* __restrict__ h,
                                                const int* __restrict__ rp,
                                                const u16* __restrict__ col,
                                                const float* __restrict__ dis,
                                                const float* __restrict__ bias,
                                                u16* __restrict__ out, int N) {
  const int wid = threadIdx.x >> 6, lane = threadIdx.x & 63;
  const int i = blockIdx.x * 4 + wid;
  if (i >= N) return;
  const int sub = lane >> 4;            // 4 edge slots
  const int l16 = lane & 15;
  const int cb = l16 * 16;              // byte offset: 16 lanes x 16B = 256B row
  const float di = dis[i];
  f32x2 a2[8];
#pragma unroll
  for (int k = 0; k < 8; ++k) { a2[k][0] = 0.f; a2[k][1] = 0.f; }
  if (sub == 0) {                       // self term once
    uint4 sv = *(const uint4*)(h + (size_t)i * 256 + cb);
    fma16p2(a2, SCALED ? 1.f : di, sv);
  }
  const int e1 = rp[i + 1];
  for (int base = rp[i]; base < e1; base += 64) {
    const int me = base + lane;
    int s_l = 0; float d_l = 0.f;
    if (me < e1) { s_l = (int)col[me]; if (!SCALED) d_l = dis[s_l]; }
    const int cnt = min(64, e1 - base);
    const int cntR = (cnt + 7) & ~7;
    for (int t = 0; t < cntR; t += 8) {
      int sA = __shfl(s_l, t + sub, 64);
      int sB = __shfl(s_l, t + 4 + sub, 64);
      float dA, dB;
      if (SCALED) {                     // tail masking via predicate, no shuffle
        dA = (t + sub < cnt) ? 1.f : 0.f;
        dB = (t + 4 + sub < cnt) ? 1.f : 0.f;
      } else {
        dA = __shfl(d_l, t + sub, 64);
        dB = __shfl(d_l, t + 4 + sub, 64);
      }
      uint4 pA = *(const uint4*)(h + (size_t)sA * 256 + cb);
      uint4 pB = *(const uint4*)(h + (size_t)sB * 256 + cb);
      fma16p2(a2, dA, pA); fma16p2(a2, dB, pB);
    }
  }
#pragma unroll
  for (int k = 0; k < 8; ++k) {
    a2[k][0] += __shfl_xor(a2[k][0], 16, 64);
    a2[k][1] += __shfl_xor(a2[k][1], 16, 64);
  }
#pragma unroll
  for (int k = 0; k < 8; ++k) {
    a2[k][0] += __shfl_xor(a2[k][0], 32, 64);
    a2[k][1] += __shfl_xor(a2[k][1], 32, 64);
  }
  if (sub == 0) {
    const float inv = SCALED ? 0.25f : 1.f;   // undo SC=4 fp8 pre-scale
    const float* bp = bias + l16 * 16;
    float4 b0 = *(const float4*)(bp);
    float4 b1 = *(const float4*)(bp + 4);
    float4 b2 = *(const float4*)(bp + 8);
    float4 b3 = *(const float4*)(bp + 12);
    float bb[16] = {b0.x, b0.y, b0.z, b0.w, b1.x, b1.y, b1.z, b1.w,
                    b2.x, b2.y, b2.z, b2.w, b3.x, b3.y, b3.z, b3.w};
    float r[16];
#pragma unroll
    for (int k = 0; k < 16; ++k)
      r[k] = fmaxf(di * a2[k >> 1][k & 1] * inv + bb[k], 0.f) * di;
    uint4 o0, o1;
    o0.x = pkh(r[0], r[1]);  o0.y = pkh(r[2], r[3]);
    o0.z = pkh(r[4], r[5]);  o0.w = pkh(r[6], r[7]);
    o1.x = pkh(r[8], r[9]);  o1.y = pkh(r[10], r[11]);
    o1.z = pkh(r[12], r[13]); o1.w = pkh(r[14], r[15]);
    *(uint4*)(out + (size_t)i * 256 + l16 * 16) = o0;
    *(uint4*)(out + (size_t)i * 256 + l16 * 16 + 8) = o1;
  }
}

// final layer: h f16 [N,64] already-scaled messages (dis[src]*h3), out fp32
__global__ __launch_bounds__(256) void agg_d64(const u16* __restrict__ h,
                                               const int* __restrict__ rp,
                                               const u16* __restrict__ col,
                                               const float* __restrict__ dis,
                                               const float* __restrict__ bias,
                                               float* __restrict__ out, int N) {
  const int wid = threadIdx.x >> 6, lane = threadIdx.x & 63;
  const int i = blockIdx.x * 4 + wid;
  if (i >= N) return;
  const int grp = lane >> 3;      // edge slot 0..7
  const int l8 = lane & 7;
  const int c8 = l8 * 8;          // feature offset, 8 features/lane (16B f16)
  const float di = dis[i];
  float a[8] = {0.f, 0.f, 0.f, 0.f, 0.f, 0.f, 0.f, 0.f};
  if (grp == 0) {
    uint4 sv = *(const uint4*)(h + (size_t)i * 64 + c8);
    fma8h(a, 1.f, sv);            // input pre-scaled
  }
  const int e1 = rp[i + 1];
  for (int base = rp[i]; base < e1; base += 64) {
    int me = base + lane;
    int s_l = 0;
    if (me < e1) s_l = (int)col[me];
    const int cnt = min(64, e1 - base);
    const int cntR = (cnt + 15) & ~15;
    for (int t = 0; t < cntR; t += 16) {
      int sA = __shfl(s_l, t + grp, 64);
      int sB = __shfl(s_l, t + 8 + grp, 64);
      float dA = (t + grp < cnt) ? 1.f : 0.f;
      float dB = (t + 8 + grp < cnt) ? 1.f : 0.f;
      uint4 pA = *(const uint4*)(h + (size_t)sA * 64 + c8);
      uint4 pB = *(const uint4*)(h + (size_t)sB * 64 + c8);
      fma8h(a, dA, pA); fma8h(a, dB, pB);
    }
  }
#pragma unroll
  for (int k = 0; k < 8; ++k) a[k] += __shfl_xor(a[k], 8, 64);
#pragma unroll
  for (int k = 0; k < 8; ++k) a[k] += __shfl_xor(a[k], 16, 64);
#pragma unroll
  for (int k = 0; k < 8; ++k) a[k] += __shfl_xor(a[k], 32, 64);
  if (lane < 8) {
    float4 b0 = *(const float4*)(bias + c8);
    float4 b1 = *(const float4*)(bias + c8 + 4);
    float4 o0, o1;
    o0.x = di * a[0] + b0.x; o0.y = di * a[1] + b0.y;
    o0.z = di * a[2] + b0.z; o0.w = di * a[3] + b0.w;
    o1.x = di * a[4] + b1.x; o1.y = di * a[5] + b1.y;
    o1.z = di * a[6] + b1.z; o1.w = di * a[7] + b1.w;
    *(float4*)(out + (size_t)i * 64 + c8) = o0;
    *(float4*)(out + (size_t)i * 64 + c8 + 4) = o1;
  }
}

// ---------------- launch ----------------
extern "C" void kernel_launch(void* const* d_in, const int* in_sizes, int n_in,
                              void* d_out, int out_size, void* d_ws, size_t ws_size,
                              hipStream_t stream) {
  if (n_in < 8) return;
  const float* x = (const float*)d_in[0];
  const void* eptr = d_in[1];
  const float* W1 = (const float*)d_in[2];
  const float* b1 = (const float*)d_in[3];
  const float* W2 = (const float*)d_in[4];
  const float* b2 = (const float*)d_in[5];
  const float* W3 = (const float*)d_in[6];
  const float* b3 = (const float*)d_in[7];
  float* out = (float*)d_out;

  const int DIN = 256, DH = 256;
  const int N = in_sizes[0] / DIN;       // 50000
  const int E = in_sizes[1] / 2;         // 800000
  const int DOUT = in_sizes[6] / DH;     // 64
  const int MT = (N + 127) / 128;        // 391
  const int Mpad = MT * 128;
  const int nbuck = (N + 255) >> 8;      // 196

  auto rnd = [](size_t b) { return (b + 255) & ~(size_t)255; };
  size_t required = 0;
  required += rnd((size_t)Mpad * DH * 2);            // xpad (f16 layer-2/3 input)
  required += rnd((size_t)Mpad * DH);                // hbuf (fp8 256B / f16 128B)
  required += rnd((size_t)E * 2);                    // col (u16)
  required += rnd((size_t)E * 4);                    // tmp (packed pairs)
  required += rnd((size_t)(N + 1) * 4);              // rp
  required += rnd((size_t)N * 4);                    // dis
  required += rnd((size_t)DIN * DH * 2);             // wt1
  required += rnd((size_t)DH * DH * 2);              // wt2
  required += rnd((size_t)DH * DOUT * 2);            // wt3
  required += rnd((size_t)256 * NCHUNK * 4);         // cnt
  if (ws_size < required || N > 65536 || nbuck > 256 || nbuck < 1 ||
      E < 128 || DOUT != 64) {
    zero_f32<<<(out_size + 255) / 256, 256, 0, stream>>>(out, out_size);
    return;
  }

  char* ws = (char*)d_ws;
  size_t off0 = 0;
  auto alloc = [&](size_t bytes) {
    char* p = ws + off0;
    off0 = (off0 + bytes + 255) & ~(size_t)255;
    return p;
  };
  u16* xpad = (u16*)alloc((size_t)Mpad * DH * 2);
  unsigned char* hbuf = (unsigned char*)alloc((size_t)Mpad * DH);
  u16* colb = (u16*)alloc((size_t)E * 2);
  unsigned* tmpb = (unsigned*)alloc((size_t)E * 4);
  int* rp = (int*)alloc((size_t)(N + 1) * 4);
  float* dis = (float*)alloc((size_t)N * 4);
  u16* wt1 = (u16*)alloc((size_t)DIN * DH * 2);
  u16* wt2 = (u16*)alloc((size_t)DH * DH * 2);
  u16* wt3 = (u16*)alloc((size_t)DH * DOUT * 2);
  int* cnt = (int*)alloc((size_t)256 * NCHUNK * 4);

  const int nb_w1 = (DIN * DH + 255) / 256;
  const int nb_w2 = (DH * DH + 255) / 256;
  const int nb_w3 = (DH * DOUT + 255) / 256;
  prep_all<<<nb_w1 + nb_w2 + nb_w3 + NCHUNK, 256, 0, stream>>>(
      W1, wt1, W2, wt2, W3, wt3, eptr, cnt,
      E, N, DIN, DH, DOUT, nb_w1, nb_w2, nb_w3);

  // csr_bucket (256 blocks) co-resident with layer-1 gemm (391 blocks):
  // 32KB LDS -> 5 blocks/CU -> 1280 slots, all 647 resident at once.
  bucket_gemm1<<<NCHUNK + MT, 256, 0, stream>>>(eptr, cnt, tmpb, x, wt1, hbuf,
                                                E, N, nbuck);
  csr_final<<<nbuck, 256, 0, stream>>>(tmpb, cnt, rp, dis, colb, N, E, nbuck);

  const int gb = (N + 3) / 4;             // per-node agg blocks (measured best)

  // layer 1 agg: unscaled fp8 h, dis gather -> prescaled f16 xpad
  agg_d256<0><<<gb, 256, 0, stream>>>(hbuf, rp, colb, dis, b1, xpad, N);
  // layer 2: gemm f16-A (prescaled) -> fp8(4*dis*h); agg without dis gather
  gemm64c<1, 0, 4, 4><<<MT, 256, 0, stream>>>(xpad, wt2, hbuf, DH, N);
  agg_d256<1><<<gb, 256, 0, stream>>>(hbuf, rp, colb, dis, b2, xpad, N);
  // layer 3: gemm -> f16 scaled msgs (128B rows); agg_d64 -> fp32 out
  gemm64c<0, 0, 1, 1><<<MT, 256, 0, stream>>>(xpad, wt3, hbuf, DOUT, N);
  agg_d64<<<gb, 256, 0, stream>>>((const u16*)hbuf, rp, colb, dis, b3, out, N);
}